// Round 3
// baseline (500.520 us; speedup 1.0000x reference)
//
#include <hip/hip_runtime.h>
#include <hip/hip_bf16.h>

typedef _Float16 half8 __attribute__((ext_vector_type(8)));
typedef float    f32x4 __attribute__((ext_vector_type(4)));

// ws layout (bytes)
#define Y_OFF    0ull
#define Y_BYTES  (33554432ull * 2ull)          // 8*256*256*64 halves, NHWC
#define TW_OFF   (Y_OFF + Y_BYTES)
#define TW_BYTES (576ull * 64ull * 2ull)       // pre-swizzled ternary weights
#define MSW_OFF  (TW_OFF + TW_BYTES)

// ---------------------------------------------------------------------------
// Kernel 1a: mean(|W|) -> msw = max(mean,1e-8) = 1/s_w.  One block, float4.
// ---------------------------------------------------------------------------
__global__ __launch_bounds__(256) void wq_reduce(const float* __restrict__ W,
                                                 float* __restrict__ msw_out) {
    __shared__ float red[256];
    int tid = threadIdx.x;
    const float4* W4 = (const float4*)W;
    float s = 0.0f;
    #pragma unroll
    for (int i = 0; i < 36; ++i) {                // 256*36 = 9216 float4 = 36864
        float4 w = W4[i * 256 + tid];
        s += fabsf(w.x) + fabsf(w.y) + fabsf(w.z) + fabsf(w.w);
    }
    red[tid] = s;
    __syncthreads();
    for (int off = 128; off > 0; off >>= 1) {
        if (tid < off) red[tid] += red[tid + off];
        __syncthreads();
    }
    if (tid == 0) msw_out[0] = fmaxf(red[0] / 36864.0f, 1e-8f);
}

// ---------------------------------------------------------------------------
// Kernel 1b: ternary quantize + pre-swizzle for MFMA A-fragments (grid-wide).
// For W element (o,c,kh,kw): k = (kh*3+kw)*64 + c
//   tw2[((k>>3)*64 + o)*8 + (k&7)]  -> one lane A-fragment = contiguous half8
// ---------------------------------------------------------------------------
__global__ __launch_bounds__(256) void wq_write(const float* __restrict__ W,
                                                const float* __restrict__ msw_p,
                                                _Float16* __restrict__ tw2) {
    int idx = blockIdx.x * 256 + threadIdx.x;    // < 36864 exactly (144 blocks)
    float s_w = 1.0f / msw_p[0];
    float t = rintf(s_w * W[idx]);
    t = fminf(1.0f, fmaxf(-1.0f, t));
    int o  = idx / 576;                          // ((o*64+c)*3+kh)*3+kw
    int r  = idx - o * 576;
    int c  = r / 9;
    int r2 = r - c * 9;
    int kh = r2 / 3;
    int kw = r2 - kh * 3;
    int k  = (kh * 3 + kw) * 64 + c;
    tw2[((k >> 3) * 64 + o) * 8 + (k & 7)] = (_Float16)t;
}

// ---------------------------------------------------------------------------
// Kernel 2 (v3): per-pixel channel-norm + int8 fake-quant, f16 NHWC out.
// Channels split across lane pairs (l, l^32): 32 regs/thread -> ~2x occupancy
// and 8 KB/wave of loads in flight -> HBM-bound for real.
// ---------------------------------------------------------------------------
__global__ __launch_bounds__(256) void norm_kernel(const float* __restrict__ x,
                                                   _Float16* __restrict__ y) {
    int wave = threadIdx.x >> 6;
    int l    = threadIdx.x & 63;
    int pl   = l & 31;                       // pixel within 32-pixel group
    int hh   = l >> 5;                       // channel half (0/1)
    int pg   = blockIdx.x * 4 + wave;        // group id, 16384 total
    int p0   = pg * 32;
    int bb   = p0 >> 16;
    int hw   = (p0 & 65535) + pl;
    const float* xp = x + ((size_t)bb * 64 + hh * 32) * 65536 + hw;

    float v[32];
    float s = 0.0f;
    #pragma unroll
    for (int c = 0; c < 32; ++c) { v[c] = xp[(size_t)c * 65536]; s += v[c]; }
    s += __shfl_xor(s, 32);
    float mu = s * (1.0f / 64.0f);

    float var = 0.0f, dmax = 0.0f;
    #pragma unroll
    for (int c = 0; c < 32; ++c) {
        float d = v[c] - mu;
        var += d * d;
        dmax = fmaxf(dmax, fabsf(d));
    }
    var  += __shfl_xor(var, 32);
    dmax  = fmaxf(dmax, __shfl_xor(dmax, 32));
    var  *= (1.0f / 64.0f);
    float r    = 1.0f / sqrtf(var + 1e-8f);
    float amax = fmaxf(dmax * r, 1e-8f);
    float s_a  = 127.0f / amax;
    float invs = amax / 127.0f;

    half8 hv[4];
    #pragma unroll
    for (int c = 0; c < 32; ++c) {
        float yn = (v[c] - mu) * r;
        float q  = rintf(s_a * yn);              // RNE == jnp.round
        q = fminf(127.0f, fmaxf(-128.0f, q));
        hv[c >> 3][c & 7] = (_Float16)(q * invs);
    }
    half8* yp = (half8*)(y + ((size_t)(p0 + pl) * 64) + hh * 32);
    #pragma unroll
    for (int j = 0; j < 4; ++j) yp[j] = hv[j];
}

// ---------------------------------------------------------------------------
// Kernel 3 (v3): implicit GEMM on mfma_f32_16x16x32_f16.
// v1 register shape (each wave: 16 o, aw[18]=72 VGPR) + 2 output rows per
// block (4-row halo) to amortize staging/barriers; v2's conflict-free CPAD
// LDS layout (odd 33-dword row stride, measured 0 conflicts).
// ---------------------------------------------------------------------------
#define CPAD 66                                   // 64 c + 2 pad halves
__global__ __launch_bounds__(256, 2) void conv_kernel(const _Float16* __restrict__ y,
                                                      const _Float16* __restrict__ tw2,
                                                      const float* __restrict__ msw_p,
                                                      const float* __restrict__ bias,
                                                      float* __restrict__ out) {
    __shared__ alignas(16) _Float16 lds[4 * 66 * CPAD];   // 34848 B

    int tid = threadIdx.x;
    int bid = blockIdx.x;
    int wt = bid & 3;
    int hb = (bid >> 2) & 127;
    int bb = bid >> 9;
    int w0 = wt * 64;
    int h0 = hb * 2;

    // ---- stage y halo tile: rows h0-1..h0+2, w0-1..w0+64, all 64 c ----
    for (int i = tid; i < 2112; i += 256) {      // 4*66*8 half8-chunks
        int cc = i & 7;
        int t8 = i >> 3;                         // r*66 + wl
        int wl = t8 % 66;
        int r  = t8 / 66;
        int hp = h0 + r - 1;
        int wp = w0 + wl - 1;
        half8 val;
        #pragma unroll
        for (int e = 0; e < 8; ++e) val[e] = (_Float16)0.0f;
        if ((unsigned)hp < 256u && (unsigned)wp < 256u)
            val = *(const half8*)(y + ((((size_t)bb * 256 + hp) * 256 + wp) * 64 + cc * 8));
        *(half8*)(lds + (r * 66 + wl) * CPAD + cc * 8) = val;
    }

    int l   = tid & 63;
    int wv  = tid >> 6;        // o-tile: o in [wv*16, wv*16+16)
    int l15 = l & 15;
    int q8  = l >> 4;

    // ---- preload weight A-fragments: 18 K-steps (72 VGPR, L2-hot) ----
    half8 aw[18];
    #pragma unroll
    for (int ks = 0; ks < 18; ++ks)
        aw[ks] = *(const half8*)(tw2 + (((ks * 4 + q8) * 64) + wv * 16 + l15) * 8);

    __syncthreads();

    float msw = *msw_p;                 // = 1/s_w
    #pragma unroll
    for (int rr = 0; rr < 2; ++rr) {
        f32x4 acc[4];
        #pragma unroll
        for (int nt = 0; nt < 4; ++nt)
            #pragma unroll
            for (int e = 0; e < 4; ++e) acc[nt][e] = 0.0f;

        #pragma unroll
        for (int ks = 0; ks < 18; ++ks) {
            int tap = ks >> 1;
            int kh  = tap / 3;
            int kw  = tap - kh * 3;
            int cbase = (ks & 1) * 32 + q8 * 8;
            const _Float16* lrow = lds + ((rr + kh) * 66 + kw + l15) * CPAD + cbase;
            #pragma unroll
            for (int nt = 0; nt < 4; ++nt) {
                half8 bf = *(const half8*)(lrow + nt * 16 * CPAD);
                acc[nt] = __builtin_amdgcn_mfma_f32_16x16x32_f16(aw[ks], bf, acc[nt], 0, 0, 0);
            }
        }

        // ---- epilogue: D[row=o_local=q8*4+reg][col=w=nt*16+l15] ----
        int hout = h0 + rr;
        size_t obase = ((size_t)bb * 64) * 65536 + (size_t)hout * 256;
        #pragma unroll
        for (int reg = 0; reg < 4; ++reg) {
            int o = wv * 16 + q8 * 4 + reg;
            float bo = bias[o];
            #pragma unroll
            for (int nt = 0; nt < 4; ++nt) {
                int w = w0 + nt * 16 + l15;
                out[obase + (size_t)o * 65536 + w] = acc[nt][reg] * msw + bo;
            }
        }
    }
}

extern "C" void kernel_launch(void* const* d_in, const int* in_sizes, int n_in,
                              void* d_out, int out_size, void* d_ws, size_t ws_size,
                              hipStream_t stream) {
    const float* x = (const float*)d_in[0];   // [8,64,256,256]
    const float* W = (const float*)d_in[1];   // [64,64,3,3]
    const float* b = (const float*)d_in[2];   // [64]
    float* out = (float*)d_out;

    char* ws = (char*)d_ws;
    _Float16* y   = (_Float16*)(ws + Y_OFF);
    _Float16* tw2 = (_Float16*)(ws + TW_OFF);
    float*    msw = (float*)(ws + MSW_OFF);

    wq_reduce<<<1, 256, 0, stream>>>(W, msw);
    wq_write<<<144, 256, 0, stream>>>(W, msw, tw2);
    norm_kernel<<<4096, 256, 0, stream>>>(x, y);
    conv_kernel<<<4096, 256, 0, stream>>>(y, tw2, msw, b, out);
}